// Round 1
// baseline (823.273 us; speedup 1.0000x reference)
//
#include <hip/hip_runtime.h>
#include <hip/hip_bf16.h>

using bf16 = __hip_bfloat16;
typedef __attribute__((ext_vector_type(16))) float f32x16;
typedef __attribute__((ext_vector_type(8))) __bf16 bf16x8;

static constexpr int Tn = 8192;           // tokens = B*S = 4*2048
static constexpr int D  = 4096;           // in features (K)
static constexpr int QO = 4096, KO = 1024, VO = 1024;
static constexpr int NO = QO + KO + VO;   // 6144 fused out features

// ---------------- cast x fp32 -> bf16 (8 elems/thread) ----------------
__global__ void cast_x_kernel(const float* __restrict__ x, bf16* __restrict__ xb) {
    size_t i = ((size_t)blockIdx.x * blockDim.x + threadIdx.x) * 8;
    float4 a = *(const float4*)(x + i);
    float4 b = *(const float4*)(x + i + 4);
    union { bf16 h[8]; uint4 u; } pk;
    pk.h[0] = __float2bfloat16(a.x); pk.h[1] = __float2bfloat16(a.y);
    pk.h[2] = __float2bfloat16(a.z); pk.h[3] = __float2bfloat16(a.w);
    pk.h[4] = __float2bfloat16(b.x); pk.h[5] = __float2bfloat16(b.y);
    pk.h[6] = __float2bfloat16(b.z); pk.h[7] = __float2bfloat16(b.w);
    *(uint4*)(xb + i) = pk.u;
}

// ------------- dequant q/k/v codes -> fused bf16 W [NO][D] -------------
__global__ void dequant_kernel(
    const int* __restrict__ qc, const float* __restrict__ qs, const float* __restrict__ qcb,
    const int* __restrict__ kc, const float* __restrict__ ks, const float* __restrict__ kcb,
    const int* __restrict__ vc, const float* __restrict__ vs, const float* __restrict__ vcb,
    bf16* __restrict__ W) {
    __shared__ float cb[48];
    int t = threadIdx.x;
    if (t < 48) cb[t] = (t < 16) ? qcb[t] : (t < 32 ? kcb[t - 16] : vcb[t - 32]);
    __syncthreads();
    size_t idx = ((size_t)blockIdx.x * 256 + t) * 8;   // elem index into W
    int o = (int)(idx >> 12);        // D == 4096 == 2^12
    int c = (int)(idx & 4095);
    const int* codes; const float* scales; int cbo; int ro;
    if (o < QO)           { codes = qc; scales = qs; cbo = 0;  ro = o; }
    else if (o < QO + KO) { codes = kc; scales = ks; cbo = 16; ro = o - QO; }
    else                  { codes = vc; scales = vs; cbo = 32; ro = o - QO - KO; }
    float s = scales[ro * (D / 128) + (c >> 7)];       // GROUP = 128
    const int4* cp = (const int4*)(codes + (size_t)ro * D + c);
    int4 c0 = cp[0], c1 = cp[1];
    union { bf16 h[8]; uint4 u; } pk;
    pk.h[0] = __float2bfloat16(cb[cbo + c0.x] * s);
    pk.h[1] = __float2bfloat16(cb[cbo + c0.y] * s);
    pk.h[2] = __float2bfloat16(cb[cbo + c0.z] * s);
    pk.h[3] = __float2bfloat16(cb[cbo + c0.w] * s);
    pk.h[4] = __float2bfloat16(cb[cbo + c1.x] * s);
    pk.h[5] = __float2bfloat16(cb[cbo + c1.y] * s);
    pk.h[6] = __float2bfloat16(cb[cbo + c1.z] * s);
    pk.h[7] = __float2bfloat16(cb[cbo + c1.w] * s);
    *(uint4*)(W + idx) = pk.u;
}

// ================= R3: 256x256 tile, 8-phase counted-vmcnt GEMM =================
// C[T,NO] = X[T,D] * W[NO,D]^T, bf16 MFMA 32x32x16.
// 512 threads = 8 waves (2M x 4N); wave tile 128x64; acc = 8 x f32x16 (128 VGPR).
// LDS 128 KiB: per operand 2 dbuf x 2 K-halves (regions of 256 rows x 32 cols).
// Per K-tile (BK=64): 4 phases {pA,pB: kh0 x (mt01|mt23), pC,pD: kh1 x ...}.
// Staging: one region of tile t+1 issued per phase of tile t (2 loads/wave).
// vmcnt ledger (per wave, 2 loads per region, issue order Akh0,Bkh0,Akh1,Bkh1):
//   wait at end of pB -> vmcnt(4): newest 4 = {t+1.Akh0, t+1.Bkh0}; guarantees
//     t.Akh1/t.Bkh1 landed before pC/pD reads (2 barriers downstream).
//   wait at end of pD -> vmcnt(4): newest 4 = {t+1.Akh1, t+1.Bkh1}; guarantees
//     t+1.Akh0/Bkh0 landed before next tile's pA/pB reads.
//   Never vmcnt(0) in steady state (T4); raw s_barrier, no compiler drain.
// LDS swizzle (T2): 16B chunk g of row r stored at slot g ^ ((r>>1)&3); staging
// pre-swizzles the GLOBAL source so global_load_lds dests stay linear; b128 frag
// reads then hit 8 distinct bank-bases per 8 rows (optimal 4-way/32 lanes).
#define BM 256
#define BN 256
#define BK 64
#define REG_ELEMS (BM * 32)   // one [dbuf][khalf] region: 256 rows x 32 bf16 = 16 KB

#define ASYNC16(g, l)                                              \
    __builtin_amdgcn_global_load_lds(                              \
        (const __attribute__((address_space(1))) void*)(g),        \
        (__attribute__((address_space(3))) void*)(l), 16, 0, 0)
#define BAR()    __builtin_amdgcn_s_barrier()
#define SCHEDB() __builtin_amdgcn_sched_barrier(0)
#define VMCNT4() asm volatile("s_waitcnt vmcnt(4)" ::: "memory")
#define VMCNT0() asm volatile("s_waitcnt vmcnt(0)" ::: "memory")

// Stage one 16 KB region (tile rows 0..255 x 32 cols): 2 insts/wave, 16 rows each.
// LDS dest linear (base + lane*16): lane l -> row R0+(l>>2), slot l&3.
// Global chunk pre-swizzled: slot s of row r must hold chunk s ^ ((r>>1)&3).
__device__ __forceinline__ void stage_region(const bf16* __restrict__ g,
                                             bf16* region, int grow0, int kcol,
                                             int wave, int lane) {
    #pragma unroll
    for (int i = 0; i < 2; ++i) {
        const int R0  = wave * 32 + i * 16;
        const int row = R0 + (lane >> 2);
        const int gch = (lane & 3) ^ ((row >> 1) & 3);
        ASYNC16(g + (size_t)(grow0 + row) * D + kcol + gch * 8, region + R0 * 32);
    }
}

template <int CUR, bool STG>
__device__ __forceinline__ void do_tile(int kt,
        const bf16* __restrict__ A, const bf16* __restrict__ Bm,
        bf16* lA, bf16* lB, f32x16 (&acc)[4][2],
        int m0, int n0, int wave, int lane, int wm, int wn) {
    const int l32  = lane & 31;
    const int lhi  = lane >> 5;
    const int skey = (l32 >> 1) & 3;   // (row>>1)&3 with rowbase % 32 == 0

    bf16* rA0 = lA + (CUR * 2 + 0) * REG_ELEMS;       // read: this tile
    bf16* rA1 = lA + (CUR * 2 + 1) * REG_ELEMS;
    bf16* rB0 = lB + (CUR * 2 + 0) * REG_ELEMS;
    bf16* rB1 = lB + (CUR * 2 + 1) * REG_ELEMS;
    bf16* sA0 = lA + ((CUR ^ 1) * 2 + 0) * REG_ELEMS; // stage: next tile
    bf16* sA1 = lA + ((CUR ^ 1) * 2 + 1) * REG_ELEMS;
    bf16* sB0 = lB + ((CUR ^ 1) * 2 + 0) * REG_ELEMS;
    bf16* sB1 = lB + ((CUR ^ 1) * 2 + 1) * REG_ELEMS;

    bf16x8 a[2][2], b[2][2];

    // ---------------- pA: kh0, mt {0,1}; stage t+1.Akh0 ----------------
    #pragma unroll
    for (int mi = 0; mi < 2; ++mi)
        #pragma unroll
        for (int kl = 0; kl < 2; ++kl)
            a[mi][kl] = *(const bf16x8*)&rA0[(wm + mi * 32 + l32) * 32 + (((kl * 2 + lhi) ^ skey) * 8)];
    #pragma unroll
    for (int nt = 0; nt < 2; ++nt)
        #pragma unroll
        for (int kl = 0; kl < 2; ++kl)
            b[nt][kl] = *(const bf16x8*)&rB0[(wn + nt * 32 + l32) * 32 + (((kl * 2 + lhi) ^ skey) * 8)];
    if (STG) stage_region(A, sA0, m0, kt + BK, wave, lane);
    BAR(); SCHEDB();
    __builtin_amdgcn_s_setprio(1);
    #pragma unroll
    for (int kl = 0; kl < 2; ++kl)
        #pragma unroll
        for (int mi = 0; mi < 2; ++mi)
            #pragma unroll
            for (int nt = 0; nt < 2; ++nt)
                acc[mi][nt] = __builtin_amdgcn_mfma_f32_32x32x16_bf16(a[mi][kl], b[nt][kl], acc[mi][nt], 0, 0, 0);
    __builtin_amdgcn_s_setprio(0);
    SCHEDB(); BAR(); SCHEDB();

    // ---------------- pB: kh0, mt {2,3}; stage t+1.Bkh0; wait W2 ----------------
    #pragma unroll
    for (int mi = 0; mi < 2; ++mi)
        #pragma unroll
        for (int kl = 0; kl < 2; ++kl)
            a[mi][kl] = *(const bf16x8*)&rA0[(wm + 64 + mi * 32 + l32) * 32 + (((kl * 2 + lhi) ^ skey) * 8)];
    if (STG) stage_region(Bm, sB0, n0, kt + BK, wave, lane);
    if (STG) { VMCNT4(); } else { VMCNT0(); }   // guarantee this tile's kh1 landed
    SCHEDB();
    BAR(); SCHEDB();
    __builtin_amdgcn_s_setprio(1);
    #pragma unroll
    for (int kl = 0; kl < 2; ++kl)
        #pragma unroll
        for (int mi = 0; mi < 2; ++mi)
            #pragma unroll
            for (int nt = 0; nt < 2; ++nt)
                acc[2 + mi][nt] = __builtin_amdgcn_mfma_f32_32x32x16_bf16(a[mi][kl], b[nt][kl], acc[2 + mi][nt], 0, 0, 0);
    __builtin_amdgcn_s_setprio(0);
    SCHEDB(); BAR(); SCHEDB();

    // ---------------- pC: kh1, mt {0,1}; stage t+1.Akh1 ----------------
    #pragma unroll
    for (int mi = 0; mi < 2; ++mi)
        #pragma unroll
        for (int kl = 0; kl < 2; ++kl)
            a[mi][kl] = *(const bf16x8*)&rA1[(wm + mi * 32 + l32) * 32 + (((kl * 2 + lhi) ^ skey) * 8)];
    #pragma unroll
    for (int nt = 0; nt < 2; ++nt)
        #pragma unroll
        for (int kl = 0; kl < 2; ++kl)
            b[nt][kl] = *(const bf16x8*)&rB1[(wn + nt * 32 + l32) * 32 + (((kl * 2 + lhi) ^ skey) * 8)];
    if (STG) stage_region(A, sA1, m0, kt + BK + 32, wave, lane);
    BAR(); SCHEDB();
    __builtin_amdgcn_s_setprio(1);
    #pragma unroll
    for (int kl = 0; kl < 2; ++kl)
        #pragma unroll
        for (int mi = 0; mi < 2; ++mi)
            #pragma unroll
            for (int nt = 0; nt < 2; ++nt)
                acc[mi][nt] = __builtin_amdgcn_mfma_f32_32x32x16_bf16(a[mi][kl], b[nt][kl], acc[mi][nt], 0, 0, 0);
    __builtin_amdgcn_s_setprio(0);
    SCHEDB(); BAR(); SCHEDB();

    // ---------------- pD: kh1, mt {2,3}; stage t+1.Bkh1; wait W1 ----------------
    #pragma unroll
    for (int mi = 0; mi < 2; ++mi)
        #pragma unroll
        for (int kl = 0; kl < 2; ++kl)
            a[mi][kl] = *(const bf16x8*)&rA1[(wm + 64 + mi * 32 + l32) * 32 + (((kl * 2 + lhi) ^ skey) * 8)];
    if (STG) {
        stage_region(Bm, sB1, n0, kt + BK + 32, wave, lane);
        VMCNT4();                                // guarantee t+1's kh0 landed
        SCHEDB();
    }
    BAR(); SCHEDB();
    __builtin_amdgcn_s_setprio(1);
    #pragma unroll
    for (int kl = 0; kl < 2; ++kl)
        #pragma unroll
        for (int mi = 0; mi < 2; ++mi)
            #pragma unroll
            for (int nt = 0; nt < 2; ++nt)
                acc[2 + mi][nt] = __builtin_amdgcn_mfma_f32_32x32x16_bf16(a[mi][kl], b[nt][kl], acc[2 + mi][nt], 0, 0, 0);
    __builtin_amdgcn_s_setprio(0);
    SCHEDB(); BAR(); SCHEDB();
}

__global__ __launch_bounds__(512, 2) void gemm_qkv_kernel(
    const bf16* __restrict__ A,   // [Tn][D] bf16
    const bf16* __restrict__ Bm,  // [NO][D] bf16
    float* __restrict__ out) {
    __shared__ __align__(16) bf16 lA[4 * REG_ELEMS];  // 64 KB: [dbuf*2+khalf]
    __shared__ __align__(16) bf16 lB[4 * REG_ELEMS];  // 64 KB

    const int t    = threadIdx.x;
    const int wave = t >> 6;
    const int lane = t & 63;

    // XCD-bijective swizzle: 768 blocks, 768 % 8 == 0 -> simple form valid.
    const int wg  = blockIdx.x;
    const int swz = (wg & 7) * 96 + (wg >> 3);
    const int bx  = swz % 24;            // N block (24 = NO/BN)
    const int by  = swz / 24;            // M block (32 = Tn/BM)
    const int m0  = by * BM;
    const int n0  = bx * BN;

    const int wm = (wave >> 2) * 128;    // wave M offset (2 M-waves)
    const int wn = (wave & 3) * 64;      // wave N offset (4 N-waves)

    f32x16 acc[4][2] = {};

    // prologue: stage tile0's 4 regions; vmcnt(4) leaves kh1 in flight
    stage_region(A,  lA + 0 * REG_ELEMS, m0, 0,  wave, lane);
    stage_region(Bm, lB + 0 * REG_ELEMS, n0, 0,  wave, lane);
    stage_region(A,  lA + 1 * REG_ELEMS, m0, 32, wave, lane);
    stage_region(Bm, lB + 1 * REG_ELEMS, n0, 32, wave, lane);
    VMCNT4(); SCHEDB(); BAR(); SCHEDB();

    int kt = 0;
    #pragma unroll 1
    for (int it = 0; it < (D / (2 * BK)) - 1; ++it, kt += 2 * BK) {
        do_tile<0, true>(kt,      A, Bm, lA, lB, acc, m0, n0, wave, lane, wm, wn);
        do_tile<1, true>(kt + BK, A, Bm, lA, lB, acc, m0, n0, wave, lane, wm, wn);
    }
    do_tile<0, true >(kt,      A, Bm, lA, lB, acc, m0, n0, wave, lane, wm, wn);
    do_tile<1, false>(kt + BK, A, Bm, lA, lB, acc, m0, n0, wave, lane, wm, wn);

    // epilogue: map fused column block -> q/k/v output region
    float* base; int ld, c0;
    if (n0 < QO)           { base = out;                                     ld = QO; c0 = n0; }
    else if (n0 < QO + KO) { base = out + (size_t)Tn * QO;                   ld = KO; c0 = n0 - QO; }
    else                   { base = out + (size_t)Tn * QO + (size_t)Tn * KO; ld = VO; c0 = n0 - QO - KO; }

    // 32x32 C/D layout (m74/m101): col = lane&31, row = (reg&3) + 8*(reg>>2) + 4*(lane>>5)
    const int l32 = lane & 31;
    const int lhi = lane >> 5;
    #pragma unroll
    for (int mt = 0; mt < 4; ++mt) {
        #pragma unroll
        for (int nt = 0; nt < 2; ++nt) {
            int gc = c0 + wn + nt * 32 + l32;
            #pragma unroll
            for (int reg = 0; reg < 16; ++reg) {
                int gr = m0 + wm + mt * 32 + (reg & 3) + 8 * (reg >> 2) + 4 * lhi;
                base[(size_t)gr * ld + gc] = acc[mt][nt][reg];
            }
        }
    }
}

extern "C" void kernel_launch(void* const* d_in, const int* in_sizes, int n_in,
                              void* d_out, int out_size, void* d_ws, size_t ws_size,
                              hipStream_t stream) {
    const float* x   = (const float*)d_in[0];
    const int*   qc  = (const int*)  d_in[1];
    const float* qs  = (const float*)d_in[2];
    const float* qcb = (const float*)d_in[3];
    const int*   kc  = (const int*)  d_in[4];
    const float* ks  = (const float*)d_in[5];
    const float* kcb = (const float*)d_in[6];
    const int*   vc  = (const int*)  d_in[7];
    const float* vs  = (const float*)d_in[8];
    const float* vcb = (const float*)d_in[9];
    float* out = (float*)d_out;

    // workspace: xb = 64 MB, W = 48 MB (112 MB total)
    bf16* xb = (bf16*)d_ws;
    bf16* W  = (bf16*)((char*)d_ws + (size_t)Tn * D * sizeof(bf16));

    cast_x_kernel<<<(Tn * D) / (8 * 256), 256, 0, stream>>>(x, xb);
    dequant_kernel<<<((size_t)NO * D) / (8 * 256), 256, 0, stream>>>(
        qc, qs, qcb, kc, ks, kcb, vc, vs, vcb, W);
    gemm_qkv_kernel<<<dim3((NO / BN) * (Tn / BM)), 512, 0, stream>>>(xb, W, out);
}

// Round 2
// 818.252 us; speedup vs baseline: 1.0061x; 1.0061x over previous
//
#include <hip/hip_runtime.h>
#include <hip/hip_bf16.h>

using bf16 = __hip_bfloat16;
typedef __attribute__((ext_vector_type(16))) float f32x16;
typedef __attribute__((ext_vector_type(8))) __bf16 bf16x8;

static constexpr int Tn = 8192;           // tokens = B*S = 4*2048
static constexpr int D  = 4096;           // in features (K)
static constexpr int QO = 4096, KO = 1024, VO = 1024;
static constexpr int NO = QO + KO + VO;   // 6144 fused out features

static constexpr int CAST_BLOCKS = (Tn * D) / (8 * 256);        // 16384
static constexpr int DQ_BLOCKS   = (NO * D) / (8 * 256);        // 12288

// --------- fused prep: cast x fp32->bf16 AND dequant q/k/v -> W ----------
__global__ void prep_kernel(
    const float* __restrict__ x, bf16* __restrict__ xb,
    const int* __restrict__ qc, const float* __restrict__ qs, const float* __restrict__ qcb,
    const int* __restrict__ kc, const float* __restrict__ ks, const float* __restrict__ kcb,
    const int* __restrict__ vc, const float* __restrict__ vs, const float* __restrict__ vcb,
    bf16* __restrict__ W) {
    int t = threadIdx.x;
    if (blockIdx.x < CAST_BLOCKS) {
        size_t i = ((size_t)blockIdx.x * 256 + t) * 8;
        float4 a = *(const float4*)(x + i);
        float4 b = *(const float4*)(x + i + 4);
        union { bf16 h[8]; uint4 u; } pk;
        pk.h[0] = __float2bfloat16(a.x); pk.h[1] = __float2bfloat16(a.y);
        pk.h[2] = __float2bfloat16(a.z); pk.h[3] = __float2bfloat16(a.w);
        pk.h[4] = __float2bfloat16(b.x); pk.h[5] = __float2bfloat16(b.y);
        pk.h[6] = __float2bfloat16(b.z); pk.h[7] = __float2bfloat16(b.w);
        *(uint4*)(xb + i) = pk.u;
        return;
    }
    __shared__ float cb[48];
    if (t < 48) cb[t] = (t < 16) ? qcb[t] : (t < 32 ? kcb[t - 16] : vcb[t - 32]);
    __syncthreads();
    size_t idx = ((size_t)(blockIdx.x - CAST_BLOCKS) * 256 + t) * 8;   // elem index into W
    int o = (int)(idx >> 12);        // D == 4096 == 2^12
    int c = (int)(idx & 4095);
    const int* codes; const float* scales; int cbo; int ro;
    if (o < QO)           { codes = qc; scales = qs; cbo = 0;  ro = o; }
    else if (o < QO + KO) { codes = kc; scales = ks; cbo = 16; ro = o - QO; }
    else                  { codes = vc; scales = vs; cbo = 32; ro = o - QO - KO; }
    float s = scales[ro * (D / 128) + (c >> 7)];       // GROUP = 128
    const int4* cp = (const int4*)(codes + (size_t)ro * D + c);
    int4 c0 = cp[0], c1 = cp[1];
    union { bf16 h[8]; uint4 u; } pk;
    pk.h[0] = __float2bfloat16(cb[cbo + c0.x] * s);
    pk.h[1] = __float2bfloat16(cb[cbo + c0.y] * s);
    pk.h[2] = __float2bfloat16(cb[cbo + c0.z] * s);
    pk.h[3] = __float2bfloat16(cb[cbo + c0.w] * s);
    pk.h[4] = __float2bfloat16(cb[cbo + c1.x] * s);
    pk.h[5] = __float2bfloat16(cb[cbo + c1.y] * s);
    pk.h[6] = __float2bfloat16(cb[cbo + c1.z] * s);
    pk.h[7] = __float2bfloat16(cb[cbo + c1.w] * s);
    *(uint4*)(W + idx) = pk.u;
}

// ================= R4: 256x256 8-phase counted-vmcnt GEMM, fixed LDS swizzle ===
// C[T,NO] = X[T,D] * W[NO,D]^T, bf16 MFMA 32x32x16.
// 512 threads = 8 waves (2M x 4N); wave tile 128x64; acc = 8 x f32x16.
// LDS 128 KiB: per operand 2 dbuf x 2 K-halves; region = 16 KB.
//
// R4 change (theory-driven): region reshaped [256 rows][32 bf16] (64B rows,
// only 4 x 16B slots -> even/odd rows split bank-groups {0-3}/{4-7} -> 8
// lanes/group = 2x LDS-read time; measured 37.75M conflicts ~= 4 cyc/read)
//   ==> [128 lines][8 x 16B slots]: line L packs rows (2L, 2L+1);
//       slot(r,c) = (2c + (r&1)) ^ ((r>>1)&7)   (3-bit key, attn-proven form).
// Any 32-lane fragment read now hits each 4-bank group exactly 4x (optimal).
// Staging keeps linear LDS dest (global_load_lds requirement); the per-lane
// GLOBAL source applies the inverse map (both-sides-or-neither, rule 21).
// vmcnt ledger unchanged from R3 (counted vmcnt(4), never 0 in steady state).
#define BM 256
#define BN 256
#define BK 64
#define REG_ELEMS (BM * 32)   // one [dbuf][khalf] region: 16 KB

#define ASYNC16(g, l)                                              \
    __builtin_amdgcn_global_load_lds(                              \
        (const __attribute__((address_space(1))) void*)(g),        \
        (__attribute__((address_space(3))) void*)(l), 16, 0, 0)
#define BAR()    __builtin_amdgcn_s_barrier()
#define SCHEDB() __builtin_amdgcn_sched_barrier(0)
#define VMCNT4() asm volatile("s_waitcnt vmcnt(4)" ::: "memory")
#define VMCNT0() asm volatile("s_waitcnt vmcnt(0)" ::: "memory")

// 16B-unit index within a region for (row r in 0..255, 16B chunk c in 0..3)
__device__ __forceinline__ int reg_off16(int r, int c) {
    return ((r >> 1) << 3) | ((((c << 1) | (r & 1)) ^ ((r >> 1) & 7)));
}

// Stage one 16 KB region: 2 insts/wave, each writes 1 KB at linear LDS
// [base + lane*16]. Linear slot S holds (row,chunk) = inverse of reg_off16.
__device__ __forceinline__ void stage_region(const bf16* __restrict__ g,
                                             bf16* region, int grow0, int kcol,
                                             int wave, int lane) {
    #pragma unroll
    for (int i = 0; i < 2; ++i) {
        const int S    = (wave * 2 + i) * 64 + lane;   // linear 16B-slot index
        const int line = S >> 3;
        const int u    = (S & 7) ^ (line & 7);
        const int row  = (line << 1) | (u & 1);
        const int c    = u >> 1;
        ASYNC16(g + (size_t)(grow0 + row) * D + kcol + c * 8,
                region + (size_t)(wave * 2 + i) * 512);
    }
}

template <int CUR, bool STG>
__device__ __forceinline__ void do_tile(int kt,
        const bf16* __restrict__ A, const bf16* __restrict__ Bm,
        bf16* lA, bf16* lB, f32x16 (&acc)[4][2],
        int m0, int n0, int wave, int lane, int wm, int wn) {
    const int l32  = lane & 31;
    const int lhi  = lane >> 5;

    bf16* rA0 = lA + (CUR * 2 + 0) * REG_ELEMS;       // read: this tile
    bf16* rA1 = lA + (CUR * 2 + 1) * REG_ELEMS;
    bf16* rB0 = lB + (CUR * 2 + 0) * REG_ELEMS;
    bf16* rB1 = lB + (CUR * 2 + 1) * REG_ELEMS;
    bf16* sA0 = lA + ((CUR ^ 1) * 2 + 0) * REG_ELEMS; // stage: next tile
    bf16* sA1 = lA + ((CUR ^ 1) * 2 + 1) * REG_ELEMS;
    bf16* sB0 = lB + ((CUR ^ 1) * 2 + 0) * REG_ELEMS;
    bf16* sB1 = lB + ((CUR ^ 1) * 2 + 1) * REG_ELEMS;

    bf16x8 a[2][2], b[2][2];

    // ---------------- pA: kh0, mt {0,1}; stage t+1.Akh0 ----------------
    #pragma unroll
    for (int mi = 0; mi < 2; ++mi)
        #pragma unroll
        for (int kl = 0; kl < 2; ++kl)
            a[mi][kl] = *(const bf16x8*)&rA0[reg_off16(wm + mi * 32 + l32, kl * 2 + lhi) * 8];
    #pragma unroll
    for (int nt = 0; nt < 2; ++nt)
        #pragma unroll
        for (int kl = 0; kl < 2; ++kl)
            b[nt][kl] = *(const bf16x8*)&rB0[reg_off16(wn + nt * 32 + l32, kl * 2 + lhi) * 8];
    if (STG) stage_region(A, sA0, m0, kt + BK, wave, lane);
    BAR(); SCHEDB();
    __builtin_amdgcn_s_setprio(1);
    #pragma unroll
    for (int kl = 0; kl < 2; ++kl)
        #pragma unroll
        for (int mi = 0; mi < 2; ++mi)
            #pragma unroll
            for (int nt = 0; nt < 2; ++nt)
                acc[mi][nt] = __builtin_amdgcn_mfma_f32_32x32x16_bf16(a[mi][kl], b[nt][kl], acc[mi][nt], 0, 0, 0);
    __builtin_amdgcn_s_setprio(0);
    SCHEDB(); BAR(); SCHEDB();

    // ---------------- pB: kh0, mt {2,3}; stage t+1.Bkh0; wait ----------------
    #pragma unroll
    for (int mi = 0; mi < 2; ++mi)
        #pragma unroll
        for (int kl = 0; kl < 2; ++kl)
            a[mi][kl] = *(const bf16x8*)&rA0[reg_off16(wm + 64 + mi * 32 + l32, kl * 2 + lhi) * 8];
    if (STG) stage_region(Bm, sB0, n0, kt + BK, wave, lane);
    if (STG) { VMCNT4(); } else { VMCNT0(); }   // guarantee this tile's kh1 landed
    SCHEDB();
    BAR(); SCHEDB();
    __builtin_amdgcn_s_setprio(1);
    #pragma unroll
    for (int kl = 0; kl < 2; ++kl)
        #pragma unroll
        for (int mi = 0; mi < 2; ++mi)
            #pragma unroll
            for (int nt = 0; nt < 2; ++nt)
                acc[2 + mi][nt] = __builtin_amdgcn_mfma_f32_32x32x16_bf16(a[mi][kl], b[nt][kl], acc[2 + mi][nt], 0, 0, 0);
    __builtin_amdgcn_s_setprio(0);
    SCHEDB(); BAR(); SCHEDB();

    // ---------------- pC: kh1, mt {0,1}; stage t+1.Akh1 ----------------
    #pragma unroll
    for (int mi = 0; mi < 2; ++mi)
        #pragma unroll
        for (int kl = 0; kl < 2; ++kl)
            a[mi][kl] = *(const bf16x8*)&rA1[reg_off16(wm + mi * 32 + l32, kl * 2 + lhi) * 8];
    #pragma unroll
    for (int nt = 0; nt < 2; ++nt)
        #pragma unroll
        for (int kl = 0; kl < 2; ++kl)
            b[nt][kl] = *(const bf16x8*)&rB1[reg_off16(wn + nt * 32 + l32, kl * 2 + lhi) * 8];
    if (STG) stage_region(A, sA1, m0, kt + BK + 32, wave, lane);
    BAR(); SCHEDB();
    __builtin_amdgcn_s_setprio(1);
    #pragma unroll
    for (int kl = 0; kl < 2; ++kl)
        #pragma unroll
        for (int mi = 0; mi < 2; ++mi)
            #pragma unroll
            for (int nt = 0; nt < 2; ++nt)
                acc[mi][nt] = __builtin_amdgcn_mfma_f32_32x32x16_bf16(a[mi][kl], b[nt][kl], acc[mi][nt], 0, 0, 0);
    __builtin_amdgcn_s_setprio(0);
    SCHEDB(); BAR(); SCHEDB();

    // ---------------- pD: kh1, mt {2,3}; stage t+1.Bkh1; wait ----------------
    #pragma unroll
    for (int mi = 0; mi < 2; ++mi)
        #pragma unroll
        for (int kl = 0; kl < 2; ++kl)
            a[mi][kl] = *(const bf16x8*)&rA1[reg_off16(wm + 64 + mi * 32 + l32, kl * 2 + lhi) * 8];
    if (STG) {
        stage_region(Bm, sB1, n0, kt + BK + 32, wave, lane);
        VMCNT4();                                // guarantee t+1's kh0 landed
        SCHEDB();
    }
    BAR(); SCHEDB();
    __builtin_amdgcn_s_setprio(1);
    #pragma unroll
    for (int kl = 0; kl < 2; ++kl)
        #pragma unroll
        for (int mi = 0; mi < 2; ++mi)
            #pragma unroll
            for (int nt = 0; nt < 2; ++nt)
                acc[2 + mi][nt] = __builtin_amdgcn_mfma_f32_32x32x16_bf16(a[mi][kl], b[nt][kl], acc[2 + mi][nt], 0, 0, 0);
    __builtin_amdgcn_s_setprio(0);
    SCHEDB(); BAR(); SCHEDB();
}

__global__ __launch_bounds__(512, 2) void gemm_qkv_kernel(
    const bf16* __restrict__ A,   // [Tn][D] bf16
    const bf16* __restrict__ Bm,  // [NO][D] bf16
    float* __restrict__ out) {
    __shared__ __align__(16) bf16 lA[4 * REG_ELEMS];  // 64 KB: [dbuf*2+khalf]
    __shared__ __align__(16) bf16 lB[4 * REG_ELEMS];  // 64 KB

    const int t    = threadIdx.x;
    const int wave = t >> 6;
    const int lane = t & 63;

    // XCD-bijective swizzle: 768 blocks, 768 % 8 == 0 -> simple form valid.
    const int wg  = blockIdx.x;
    const int swz = (wg & 7) * 96 + (wg >> 3);
    const int bx  = swz % 24;            // N block (24 = NO/BN)
    const int by  = swz / 24;            // M block (32 = Tn/BM)
    const int m0  = by * BM;
    const int n0  = bx * BN;

    const int wm = (wave >> 2) * 128;    // wave M offset (2 M-waves)
    const int wn = (wave & 3) * 64;      // wave N offset (4 N-waves)

    f32x16 acc[4][2] = {};

    // prologue: stage tile0's 4 regions; vmcnt(4) leaves kh1 in flight
    stage_region(A,  lA + 0 * REG_ELEMS, m0, 0,  wave, lane);
    stage_region(Bm, lB + 0 * REG_ELEMS, n0, 0,  wave, lane);
    stage_region(A,  lA + 1 * REG_ELEMS, m0, 32, wave, lane);
    stage_region(Bm, lB + 1 * REG_ELEMS, n0, 32, wave, lane);
    VMCNT4(); SCHEDB(); BAR(); SCHEDB();

    int kt = 0;
    #pragma unroll 1
    for (int it = 0; it < (D / (2 * BK)) - 1; ++it, kt += 2 * BK) {
        do_tile<0, true>(kt,      A, Bm, lA, lB, acc, m0, n0, wave, lane, wm, wn);
        do_tile<1, true>(kt + BK, A, Bm, lA, lB, acc, m0, n0, wave, lane, wm, wn);
    }
    do_tile<0, true >(kt,      A, Bm, lA, lB, acc, m0, n0, wave, lane, wm, wn);
    do_tile<1, false>(kt + BK, A, Bm, lA, lB, acc, m0, n0, wave, lane, wm, wn);

    // epilogue: map fused column block -> q/k/v output region
    float* base; int ld, c0;
    if (n0 < QO)           { base = out;                                     ld = QO; c0 = n0; }
    else if (n0 < QO + KO) { base = out + (size_t)Tn * QO;                   ld = KO; c0 = n0 - QO; }
    else                   { base = out + (size_t)Tn * QO + (size_t)Tn * KO; ld = VO; c0 = n0 - QO - KO; }

    // 32x32 C/D layout (m74/m101): col = lane&31, row = (reg&3) + 8*(reg>>2) + 4*(lane>>5)
    const int l32 = lane & 31;
    const int lhi = lane >> 5;
    #pragma unroll
    for (int mt = 0; mt < 4; ++mt) {
        #pragma unroll
        for (int nt = 0; nt < 2; ++nt) {
            int gc = c0 + wn + nt * 32 + l32;
            #pragma unroll
            for (int reg = 0; reg < 16; ++reg) {
                int gr = m0 + wm + mt * 32 + (reg & 3) + 8 * (reg >> 2) + 4 * lhi;
                base[(size_t)gr * ld + gc] = acc[mt][nt][reg];
            }
        }
    }
}

extern "C" void kernel_launch(void* const* d_in, const int* in_sizes, int n_in,
                              void* d_out, int out_size, void* d_ws, size_t ws_size,
                              hipStream_t stream) {
    const float* x   = (const float*)d_in[0];
    const int*   qc  = (const int*)  d_in[1];
    const float* qs  = (const float*)d_in[2];
    const float* qcb = (const float*)d_in[3];
    const int*   kc  = (const int*)  d_in[4];
    const float* ks  = (const float*)d_in[5];
    const float* kcb = (const float*)d_in[6];
    const int*   vc  = (const int*)  d_in[7];
    const float* vs  = (const float*)d_in[8];
    const float* vcb = (const float*)d_in[9];
    float* out = (float*)d_out;

    // workspace: xb = 64 MB, W = 48 MB (112 MB total)
    bf16* xb = (bf16*)d_ws;
    bf16* W  = (bf16*)((char*)d_ws + (size_t)Tn * D * sizeof(bf16));

    prep_kernel<<<CAST_BLOCKS + DQ_BLOCKS, 256, 0, stream>>>(
        x, xb, qc, qs, qcb, kc, ks, kcb, vc, vs, vcb, W);
    gemm_qkv_kernel<<<dim3((NO / BN) * (Tn / BM)), 512, 0, stream>>>(xb, W, out);
}

// Round 3
// 781.902 us; speedup vs baseline: 1.0529x; 1.0465x over previous
//
#include <hip/hip_runtime.h>
#include <hip/hip_bf16.h>

using bf16 = __hip_bfloat16;
typedef __attribute__((ext_vector_type(16))) float f32x16;
typedef __attribute__((ext_vector_type(8))) __bf16 bf16x8;

static constexpr int Tn = 8192;           // tokens = B*S = 4*2048
static constexpr int D  = 4096;           // in features (K)
static constexpr int QO = 4096, KO = 1024, VO = 1024;
static constexpr int NO = QO + KO + VO;   // 6144 fused out features

static constexpr int CAST_BLOCKS = (Tn * D) / (8 * 256);        // 16384
static constexpr int DQ_BLOCKS   = (NO * D) / (8 * 256);        // 12288

// --------- fused prep: cast x fp32->bf16 AND dequant q/k/v -> W ----------
__global__ void prep_kernel(
    const float* __restrict__ x, bf16* __restrict__ xb,
    const int* __restrict__ qc, const float* __restrict__ qs, const float* __restrict__ qcb,
    const int* __restrict__ kc, const float* __restrict__ ks, const float* __restrict__ kcb,
    const int* __restrict__ vc, const float* __restrict__ vs, const float* __restrict__ vcb,
    bf16* __restrict__ W) {
    int t = threadIdx.x;
    if (blockIdx.x < CAST_BLOCKS) {
        size_t i = ((size_t)blockIdx.x * 256 + t) * 8;
        float4 a = *(const float4*)(x + i);
        float4 b = *(const float4*)(x + i + 4);
        union { bf16 h[8]; uint4 u; } pk;
        pk.h[0] = __float2bfloat16(a.x); pk.h[1] = __float2bfloat16(a.y);
        pk.h[2] = __float2bfloat16(a.z); pk.h[3] = __float2bfloat16(a.w);
        pk.h[4] = __float2bfloat16(b.x); pk.h[5] = __float2bfloat16(b.y);
        pk.h[6] = __float2bfloat16(b.z); pk.h[7] = __float2bfloat16(b.w);
        *(uint4*)(xb + i) = pk.u;
        return;
    }
    __shared__ float cb[48];
    if (t < 48) cb[t] = (t < 16) ? qcb[t] : (t < 32 ? kcb[t - 16] : vcb[t - 32]);
    __syncthreads();
    size_t idx = ((size_t)(blockIdx.x - CAST_BLOCKS) * 256 + t) * 8;   // elem index into W
    int o = (int)(idx >> 12);        // D == 4096 == 2^12
    int c = (int)(idx & 4095);
    const int* codes; const float* scales; int cbo; int ro;
    if (o < QO)           { codes = qc; scales = qs; cbo = 0;  ro = o; }
    else if (o < QO + KO) { codes = kc; scales = ks; cbo = 16; ro = o - QO; }
    else                  { codes = vc; scales = vs; cbo = 32; ro = o - QO - KO; }
    float s = scales[ro * (D / 128) + (c >> 7)];       // GROUP = 128
    const int4* cp = (const int4*)(codes + (size_t)ro * D + c);
    int4 c0 = cp[0], c1 = cp[1];
    union { bf16 h[8]; uint4 u; } pk;
    pk.h[0] = __float2bfloat16(cb[cbo + c0.x] * s);
    pk.h[1] = __float2bfloat16(cb[cbo + c0.y] * s);
    pk.h[2] = __float2bfloat16(cb[cbo + c0.z] * s);
    pk.h[3] = __float2bfloat16(cb[cbo + c0.w] * s);
    pk.h[4] = __float2bfloat16(cb[cbo + c1.x] * s);
    pk.h[5] = __float2bfloat16(cb[cbo + c1.y] * s);
    pk.h[6] = __float2bfloat16(cb[cbo + c1.z] * s);
    pk.h[7] = __float2bfloat16(cb[cbo + c1.w] * s);
    *(uint4*)(W + idx) = pk.u;
}

// ============ R5: 256x256 GEMM, 2 barriers per K-tile (was 8) ============
// C[T,NO] = X[T,D] * W[NO,D]^T, bf16 MFMA 32x32x16.
// 512 threads = 8 waves (2M x 4N); wave tile 128x64; acc = 8 x f32x16.
// LDS 128 KiB: per operand 2 dbuf x 2 K-halves; region = 16 KB.
//
// R4 post-mortem: conflicts -> 0 but util stuck at 34%. Cycle model (fixed
// 4x unit error): per K-tile per SIMD, MFMA = 2065 cyc; measured tile time
// ~6000 cyc => ~3900 cyc overhead = 8 barriers x ~375 cyc lockstep cost
// (matches m201's 62% at 2x MFMA per barrier). Fix: merge the 4 phases into
// 2 halves with ONE barrier each. Hazard audit:
//   RAW (stage->read): h0-end vmcnt(4)+BAR gates this tile's kh1 reads;
//     h1-end vmcnt(4)+BAR gates next tile's kh0 reads. (ledger per wave:
//     4 stages/half; <=4 outstanding => previous half's 4 landed.)
//   WAR (read->stage overwrite): nearest pair is t.h0 reads vs t+1.h0 stage
//     = 2 barriers apart even with max 1-region wave slip. Safe.
// Slip between barriers lets one wave's ds-read drain overlap another's
// MFMA cluster; setprio(1) around MFMA now has roles to arbitrate (T5).
// sched_barrier(0) pinned at each BAR: compile-time hoist of ds_reads across
// the barrier would break the cross-wave RAW gate (rule 18/21).
#define BM 256
#define BN 256
#define BK 64
#define REG_ELEMS (BM * 32)   // one [dbuf][khalf] region: 16 KB

#define ASYNC16(g, l)                                              \
    __builtin_amdgcn_global_load_lds(                              \
        (const __attribute__((address_space(1))) void*)(g),        \
        (__attribute__((address_space(3))) void*)(l), 16, 0, 0)
#define BAR()    __builtin_amdgcn_s_barrier()
#define SCHEDB() __builtin_amdgcn_sched_barrier(0)
#define VMCNT4() asm volatile("s_waitcnt vmcnt(4)" ::: "memory")
#define VMCNT0() asm volatile("s_waitcnt vmcnt(0)" ::: "memory")

// 16B-unit index within a region for (row r in 0..255, 16B chunk c in 0..3)
// line L = r>>1 packs rows (2L,2L+1); slot = (2c+(r&1)) ^ (L&7). Verified
// conflict-free in R4 (SQ_LDS_BANK_CONFLICT 3.78e7 -> 0).
__device__ __forceinline__ int reg_off16(int r, int c) {
    return ((r >> 1) << 3) | ((((c << 1) | (r & 1)) ^ ((r >> 1) & 7)));
}

// Stage one 16 KB region: 2 insts/wave, each writes 1 KB at linear LDS
// [base + lane*16]. Linear slot S holds (row,chunk) = inverse of reg_off16.
__device__ __forceinline__ void stage_region(const bf16* __restrict__ g,
                                             bf16* region, int grow0, int kcol,
                                             int wave, int lane) {
    #pragma unroll
    for (int i = 0; i < 2; ++i) {
        const int S    = (wave * 2 + i) * 64 + lane;   // linear 16B-slot index
        const int line = S >> 3;
        const int u    = (S & 7) ^ (line & 7);
        const int row  = (line << 1) | (u & 1);
        const int c    = u >> 1;
        ASYNC16(g + (size_t)(grow0 + row) * D + kcol + c * 8,
                region + (size_t)(wave * 2 + i) * 512);
    }
}

template <int CUR, bool STG>
__device__ __forceinline__ void do_tile(int kt,
        const bf16* __restrict__ A, const bf16* __restrict__ Bm,
        bf16* lA, bf16* lB, f32x16 (&acc)[4][2],
        int m0, int n0, int wave, int lane, int wm, int wn) {
    const int l32  = lane & 31;
    const int lhi  = lane >> 5;

    bf16* rA[2] = { lA + (CUR * 2 + 0) * REG_ELEMS, lA + (CUR * 2 + 1) * REG_ELEMS };
    bf16* rB[2] = { lB + (CUR * 2 + 0) * REG_ELEMS, lB + (CUR * 2 + 1) * REG_ELEMS };
    bf16* sA[2] = { lA + ((CUR ^ 1) * 2 + 0) * REG_ELEMS, lA + ((CUR ^ 1) * 2 + 1) * REG_ELEMS };
    bf16* sB[2] = { lB + ((CUR ^ 1) * 2 + 0) * REG_ELEMS, lB + ((CUR ^ 1) * 2 + 1) * REG_ELEMS };

    #pragma unroll
    for (int h = 0; h < 2; ++h) {
        bf16x8 a01[2][2], a23[2][2], b[2][2];
        // 12 x ds_read_b128: all fragments for this K-half (K=32)
        #pragma unroll
        for (int mi = 0; mi < 2; ++mi)
            #pragma unroll
            for (int kl = 0; kl < 2; ++kl)
                a01[mi][kl] = *(const bf16x8*)&rA[h][reg_off16(wm + mi * 32 + l32, kl * 2 + lhi) * 8];
        #pragma unroll
        for (int nt = 0; nt < 2; ++nt)
            #pragma unroll
            for (int kl = 0; kl < 2; ++kl)
                b[nt][kl] = *(const bf16x8*)&rB[h][reg_off16(wn + nt * 32 + l32, kl * 2 + lhi) * 8];
        #pragma unroll
        for (int mi = 0; mi < 2; ++mi)
            #pragma unroll
            for (int kl = 0; kl < 2; ++kl)
                a23[mi][kl] = *(const bf16x8*)&rA[h][reg_off16(wm + 64 + mi * 32 + l32, kl * 2 + lhi) * 8];
        // stage next tile's same K-half (4 x global_load_lds)
        if (STG) {
            stage_region(A,  sA[h], m0, kt + BK + h * 32, wave, lane);
            stage_region(Bm, sB[h], n0, kt + BK + h * 32, wave, lane);
        }
        // 16 MFMA; compiler interleaves lgkmcnt finely; slip across waves
        __builtin_amdgcn_s_setprio(1);
        #pragma unroll
        for (int kl = 0; kl < 2; ++kl)
            #pragma unroll
            for (int mi = 0; mi < 2; ++mi)
                #pragma unroll
                for (int nt = 0; nt < 2; ++nt)
                    acc[mi][nt] = __builtin_amdgcn_mfma_f32_32x32x16_bf16(a01[mi][kl], b[nt][kl], acc[mi][nt], 0, 0, 0);
        #pragma unroll
        for (int kl = 0; kl < 2; ++kl)
            #pragma unroll
            for (int mi = 0; mi < 2; ++mi)
                #pragma unroll
                for (int nt = 0; nt < 2; ++nt)
                    acc[2 + mi][nt] = __builtin_amdgcn_mfma_f32_32x32x16_bf16(a23[mi][kl], b[nt][kl], acc[2 + mi][nt], 0, 0, 0);
        __builtin_amdgcn_s_setprio(0);
        // gate: h==0 -> this tile's kh1 RAW; h==1 -> next tile's kh0 RAW
        if (STG) { VMCNT4(); SCHEDB(); BAR(); SCHEDB(); }
        else if (h == 0) { VMCNT0(); SCHEDB(); BAR(); SCHEDB(); }
        // (last tile, h==1: no further LDS reads; no barrier needed)
    }
}

__global__ __launch_bounds__(512, 2) void gemm_qkv_kernel(
    const bf16* __restrict__ A,   // [Tn][D] bf16
    const bf16* __restrict__ Bm,  // [NO][D] bf16
    float* __restrict__ out) {
    __shared__ __align__(16) bf16 lA[4 * REG_ELEMS];  // 64 KB: [dbuf*2+khalf]
    __shared__ __align__(16) bf16 lB[4 * REG_ELEMS];  // 64 KB

    const int t    = threadIdx.x;
    const int wave = t >> 6;
    const int lane = t & 63;

    // XCD-bijective swizzle: 768 blocks, 768 % 8 == 0 -> simple form valid.
    const int wg  = blockIdx.x;
    const int swz = (wg & 7) * 96 + (wg >> 3);
    const int bx  = swz % 24;            // N block (24 = NO/BN)
    const int by  = swz / 24;            // M block (32 = Tn/BM)
    const int m0  = by * BM;
    const int n0  = bx * BN;

    const int wm = (wave >> 2) * 128;    // wave M offset (2 M-waves)
    const int wn = (wave & 3) * 64;      // wave N offset (4 N-waves)

    f32x16 acc[4][2] = {};

    // prologue: stage tile0's 4 regions; vmcnt(4) leaves kh1 in flight
    stage_region(A,  lA + 0 * REG_ELEMS, m0, 0,  wave, lane);
    stage_region(Bm, lB + 0 * REG_ELEMS, n0, 0,  wave, lane);
    stage_region(A,  lA + 1 * REG_ELEMS, m0, 32, wave, lane);
    stage_region(Bm, lB + 1 * REG_ELEMS, n0, 32, wave, lane);
    VMCNT4(); SCHEDB(); BAR(); SCHEDB();

    int kt = 0;
    #pragma unroll 1
    for (int it = 0; it < (D / (2 * BK)) - 1; ++it, kt += 2 * BK) {
        do_tile<0, true>(kt,      A, Bm, lA, lB, acc, m0, n0, wave, lane, wm, wn);
        do_tile<1, true>(kt + BK, A, Bm, lA, lB, acc, m0, n0, wave, lane, wm, wn);
    }
    do_tile<0, true >(kt,      A, Bm, lA, lB, acc, m0, n0, wave, lane, wm, wn);
    do_tile<1, false>(kt + BK, A, Bm, lA, lB, acc, m0, n0, wave, lane, wm, wn);

    // epilogue: map fused column block -> q/k/v output region
    float* base; int ld, c0;
    if (n0 < QO)           { base = out;                                     ld = QO; c0 = n0; }
    else if (n0 < QO + KO) { base = out + (size_t)Tn * QO;                   ld = KO; c0 = n0 - QO; }
    else                   { base = out + (size_t)Tn * QO + (size_t)Tn * KO; ld = VO; c0 = n0 - QO - KO; }

    // 32x32 C/D layout (m74/m101): col = lane&31, row = (reg&3) + 8*(reg>>2) + 4*(lane>>5)
    const int l32 = lane & 31;
    const int lhi = lane >> 5;
    #pragma unroll
    for (int mt = 0; mt < 4; ++mt) {
        #pragma unroll
        for (int nt = 0; nt < 2; ++nt) {
            int gc = c0 + wn + nt * 32 + l32;
            #pragma unroll
            for (int reg = 0; reg < 16; ++reg) {
                int gr = m0 + wm + mt * 32 + (reg & 3) + 8 * (reg >> 2) + 4 * lhi;
                base[(size_t)gr * ld + gc] = acc[mt][nt][reg];
            }
        }
    }
}

extern "C" void kernel_launch(void* const* d_in, const int* in_sizes, int n_in,
                              void* d_out, int out_size, void* d_ws, size_t ws_size,
                              hipStream_t stream) {
    const float* x   = (const float*)d_in[0];
    const int*   qc  = (const int*)  d_in[1];
    const float* qs  = (const float*)d_in[2];
    const float* qcb = (const float*)d_in[3];
    const int*   kc  = (const int*)  d_in[4];
    const float* ks  = (const float*)d_in[5];
    const float* kcb = (const float*)d_in[6];
    const int*   vc  = (const int*)  d_in[7];
    const float* vs  = (const float*)d_in[8];
    const float* vcb = (const float*)d_in[9];
    float* out = (float*)d_out;

    // workspace: xb = 64 MB, W = 48 MB (112 MB total)
    bf16* xb = (bf16*)d_ws;
    bf16* W  = (bf16*)((char*)d_ws + (size_t)Tn * D * sizeof(bf16));

    prep_kernel<<<CAST_BLOCKS + DQ_BLOCKS, 256, 0, stream>>>(
        x, xb, qc, qs, qcb, kc, ks, kcb, vc, vs, vcb, W);
    gemm_qkv_kernel<<<dim3((NO / BN) * (Tn / BM)), 512, 0, stream>>>(xb, W, out);
}